// Round 8
// baseline (253.775 us; speedup 1.0000x reference)
//
#include <hip/hip_runtime.h>

#define NNODES 163842
#define INF 32
#define OUTF 32
#define KTOT (7 * INF)            // 224
#define OPW 8                     // outputs per thread (OUTF / 4 waves)
#define NPB 64                    // nodes per block
#define ROWS (NPB * 7)            // 448 gathered rows per block
#define CALLS (ROWS / 8)          // 56 global_load_lds calls (each: 8 rows x 8 chunks)
#define CPW (CALLS / 4)           // 14 calls per wave

typedef unsigned int u32;

// Transpose W [32, 224] row-major -> Wt [224, 32] so main-kernel W reads are
// wave-uniform scalar loads.
__global__ void transpose_W_kernel(const float* __restrict__ W,
                                   float* __restrict__ Wt) {
    int i = blockIdx.x * blockDim.x + threadIdx.x;
    if (i < KTOT * OUTF) {
        int k = i / OUTF;
        int o = i % OUTF;
        Wt[k * OUTF + o] = W[o * KTOT + k];
    }
}

// Block = 256 threads = 4 waves, 64 nodes. Stage all 448 neighbor rows into
// LDS via async global_load_lds (per-lane global addr, linear LDS dest),
// then FMA from LDS with wave-uniform W.
// LDS chunk swizzle: row r (node n=r/7), 16B chunk c of the row is stored at
// physical chunk slot (c ^ (n&7)) — applied on BOTH fill-source and read.
__global__ __launch_bounds__(256, 2) void onering_gather_lds_kernel(
    const float* __restrict__ x,
    const int* __restrict__ idx,
    const float* __restrict__ Wt,
    const float* __restrict__ b,
    float* __restrict__ out) {
    __shared__ float lds[ROWS * INF];   // 57344 B

    const int tid  = threadIdx.x;
    const int lane = tid & 63;
    const int wq   = tid >> 6;          // wave id 0..3 == output group
    const int block0 = blockIdx.x * NPB;
    const int base7  = block0 * 7;

    // ---- gather stage: each wave issues 14 async 1KB gathers ----
    const int lsub   = lane >> 3;       // row-within-call 0..7
    const int c_phys = lane & 7;        // physical 16B chunk slot
#pragma unroll
    for (int qq = 0; qq < CPW; ++qq) {
        int q = wq * CPW + qq;                       // wave-uniform call id
        int r = q * 8 + lsub;                        // row in block 0..447
        int n = r / 7;                               // node-in-block of row r
        int c_data = c_phys ^ (n & 7);               // which data chunk this slot holds
        int rowi = base7 + r;
        rowi = min(rowi, 7 * NNODES - 1);            // tail clamp
        int xi = idx[rowi];
        const float* gsrc = x + (size_t)xi * INF + c_data * 4;
        float* ldst = lds + q * 256;                 // 1KB per call, wave-uniform base
        __builtin_amdgcn_global_load_lds(
            (const __attribute__((address_space(1))) void*)gsrc,
            (__attribute__((address_space(3))) void*)ldst,
            16, 0, 0);
    }
    __syncthreads();   // drains vmcnt before any LDS read

    // ---- compute stage: node = lane, outputs [wq*8, wq*8+8) ----
    const int n  = lane;
    const int g  = block0 + n;
    const int nx = n & 7;

    float acc[OPW];
#pragma unroll
    for (int o = 0; o < OPW; ++o) acc[o] = b[wq * OPW + o];

#pragma unroll
    for (int j = 0; j < 7; ++j) {
        const float* rowbase = lds + (n * 7 + j) * INF;
#pragma unroll
        for (int c = 0; c < 8; ++c) {
            int phys = c ^ nx;                       // undo fill swizzle
            float4 v = *(const float4*)(rowbase + phys * 4);
            const float* w0 = Wt + (j * INF + c * 4) * OUTF + wq * OPW;  // uniform -> s_load
            const float* vf = (const float*)&v;
#pragma unroll
            for (int t = 0; t < 4; ++t) {
#pragma unroll
                for (int o = 0; o < OPW; ++o) {
                    acc[o] = fmaf(vf[t], w0[t * OUTF + o], acc[o]);
                }
            }
        }
    }

    if (g < NNODES) {
        float4* op = (float4*)(out + (size_t)g * OUTF + wq * OPW);
        op[0] = *((float4*)&acc[0]);
        op[1] = *((float4*)&acc[4]);
    }
}

extern "C" void kernel_launch(void* const* d_in, const int* in_sizes, int n_in,
                              void* d_out, int out_size, void* d_ws, size_t ws_size,
                              hipStream_t stream) {
    const float* x   = (const float*)d_in[0];
    const int*   idx = (const int*)d_in[1];
    const float* W   = (const float*)d_in[2];
    const float* b   = (const float*)d_in[3];
    float* out = (float*)d_out;
    float* Wt  = (float*)d_ws;   // 224*32 floats = 28 KB

    transpose_W_kernel<<<(KTOT * OUTF + 255) / 256, 256, 0, stream>>>(W, Wt);

    int grid = (NNODES + NPB - 1) / NPB;  // 2561
    onering_gather_lds_kernel<<<grid, 256, 0, stream>>>(x, idx, Wt, b, out);
}

// Round 9
// 174.219 us; speedup vs baseline: 1.4566x; 1.4566x over previous
//
#include <hip/hip_runtime.h>

#define NNODES 163842
#define INF 32
#define OUTF 32
#define KTOT (7 * INF)   // 224
#define OPW 8            // outputs per thread (OUTF / 4 waves)

// Repack W [32, 224] row-major -> Wt2 phase-major:
// Wt2[((c*7 + j)*4 + t)*32 + o] = W[o*224 + j*32 + c*4 + t]
// so each compute phase c reads 896 contiguous bytes (wave-uniform -> s_load).
__global__ void repack_W_kernel(const float* __restrict__ W,
                                float* __restrict__ Wt2) {
    int i = blockIdx.x * blockDim.x + threadIdx.x;
    if (i < KTOT * OUTF) {
        int kk = i >> 5;          // 0..223 (original k index)
        int oo = i & 31;          // output channel
        int j = kk >> 5;          // neighbor 0..6
        int f = kk & 31;          // feature 0..31
        int c = f >> 2;           // chunk 0..7
        int t = f & 3;            // elem in chunk
        Wt2[(((c * 7 + j) << 2) + t) * 32 + oo] = W[oo * KTOT + kk];
    }
}

// Block = 256 threads = 4 waves over 64 nodes; wave og computes outputs
// [og*8, og*8+8). Chunk-major pipeline: phase c loads 16B chunk c of all 7
// neighbor rows (7 independent global loads, double-buffered) then does
// 224 FMAs against wave-uniform Wt2.
__global__ __launch_bounds__(256) void onering_chunk_kernel(
    const float* __restrict__ x,
    const int* __restrict__ idx,
    const float* __restrict__ Wt2,
    const float* __restrict__ b,
    float* __restrict__ out) {
    const int lane = threadIdx.x & 63;
    const int og = __builtin_amdgcn_readfirstlane(threadIdx.x >> 6);  // 0..3
    const int n = blockIdx.x * 64 + lane;
    const bool valid = (n < NNODES);
    const int nc = valid ? n : (NNODES - 1);

    // neighbor row base pointers (7 independent idx loads, 28B contiguous)
    const int base = nc * 7;
    const float* rp[7];
#pragma unroll
    for (int j = 0; j < 7; ++j) rp[j] = x + (size_t)idx[base + j] * INF;

    float acc[OPW];
#pragma unroll
    for (int o = 0; o < OPW; ++o) acc[o] = b[og * OPW + o];

    float4 bufA[7], bufB[7];
#pragma unroll
    for (int j = 0; j < 7; ++j) bufA[j] = *(const float4*)(rp[j]);

#pragma unroll
    for (int c = 0; c < 8; ++c) {
        float4* cur = (c & 1) ? bufB : bufA;   // static after full unroll
        float4* nxt = (c & 1) ? bufA : bufB;
        if (c < 7) {
#pragma unroll
            for (int j = 0; j < 7; ++j) {
                nxt[j] = *(const float4*)(rp[j] + (c + 1) * 4);
            }
        }
#pragma unroll
        for (int j = 0; j < 7; ++j) {
            const float* vf = (const float*)&cur[j];
#pragma unroll
            for (int t = 0; t < 4; ++t) {
                // wave-uniform, phase-contiguous -> scalar loads
                const float* wrow = Wt2 + (((c * 7 + j) << 2) + t) * 32 + og * OPW;
#pragma unroll
                for (int o = 0; o < OPW; ++o) {
                    acc[o] = fmaf(vf[t], wrow[o], acc[o]);
                }
            }
        }
    }

    if (valid) {
        float4* op = (float4*)(out + (size_t)n * OUTF + og * OPW);
        op[0] = *((float4*)&acc[0]);
        op[1] = *((float4*)&acc[4]);
    }
}

extern "C" void kernel_launch(void* const* d_in, const int* in_sizes, int n_in,
                              void* d_out, int out_size, void* d_ws, size_t ws_size,
                              hipStream_t stream) {
    const float* x   = (const float*)d_in[0];
    const int*   idx = (const int*)d_in[1];
    const float* W   = (const float*)d_in[2];
    const float* b   = (const float*)d_in[3];
    float* out = (float*)d_out;
    float* Wt2 = (float*)d_ws;   // 224*32 floats = 28 KB

    repack_W_kernel<<<(KTOT * OUTF + 255) / 256, 256, 0, stream>>>(W, Wt2);

    int grid = (NNODES + 63) / 64;  // 2561 blocks x 4 waves
    onering_chunk_kernel<<<grid, 256, 0, stream>>>(x, idx, Wt2, b, out);
}